// Round 4
// baseline (1197.235 us; speedup 1.0000x reference)
//
#include <hip/hip_runtime.h>
#include <hip/hip_cooperative_groups.h>
#include <math.h>

namespace cg = cooperative_groups;

#define F1 16
#define F2 8

// Single cooperative kernel: overlaps the 256MB output zero-fill (HBM-write
// bound) with the GCN compute chain (L2-atomic bound), phase-ordered by
// grid.sync().
//   P1: zero ws (deg,x1,x2)           + zero out chunk 1/5
//   P2: degree atomics                + zero out chunk 2/5
//   P3: dinv = rsqrt(deg+1)           + zero out chunk 3/5
//   P4: conv1 edge atomics            + zero out chunk 4/5
//   P5: layer1 (relu+matmul)          + zero out chunk 5/5
//   P6: conv2 edge atomics            + scatter 1.0 at directed edges
//   P7: orient scoring + scatter (overwrites the 1.0s at undirected pairs)
__global__ void __launch_bounds__(256, 4)
k_fused(const float* __restrict__ W1, const float* __restrict__ b1,
        const float* __restrict__ W2, const float* __restrict__ b2,
        const float* __restrict__ Wfc, const float* __restrict__ bfc,
        const int* __restrict__ src, const int* __restrict__ dst,
        const int2* __restrict__ ue,
        float* __restrict__ out, float* __restrict__ ws,
        int N, int E, int U)
{
    cg::grid_group grid = cg::this_grid();
    const long T = (long)gridDim.x * blockDim.x;
    const long tid = (long)blockIdx.x * blockDim.x + threadIdx.x;

    float* deg  = ws;                    // N
    float* x1   = ws + N;                // 16N
    float* x2   = x1 + (long)F1 * N;     // 8N
    float* dinv = x2 + (long)F2 * N;     // N
    float* h2   = dinv + N;              // 8N

    float4* out4 = (float4*)out;
    const long Z4 = (long)N * N / 4;
    const long c1 = Z4 / 5, c2 = Z4 * 2 / 5, c3 = Z4 * 3 / 5, c4 = Z4 * 4 / 5;
    const float4 z4 = make_float4(0.f, 0.f, 0.f, 0.f);

    // ---- P1: zero ws + out chunk
    {
        long nws4 = (long)(N + (long)F1 * N + (long)F2 * N) / 4;  // 25N/4
        float4* ws4 = (float4*)ws;
        for (long i = tid; i < nws4; i += T) ws4[i] = z4;
        for (long i = tid; i < c1; i += T) out4[i] = z4;
    }
    grid.sync();
    // ---- P2: degree atomics + out chunk
    {
        for (long e = tid; e < E; e += T) atomicAdd(&deg[dst[e]], 1.0f);
        for (long i = c1 + tid; i < c2; i += T) out4[i] = z4;
    }
    grid.sync();
    // ---- P3: dinv + out chunk
    {
        for (long i = tid; i < N; i += T) dinv[i] = rsqrtf(deg[i] + 1.0f);
        for (long i = c2 + tid; i < c3; i += T) out4[i] = z4;
    }
    grid.sync();
    // ---- P4: conv1 edge atomics + out chunk
    {
        long W = (long)E * F1;
        for (long id = tid; id < W; id += T) {
            long e = id >> 4;
            int f = (int)(id & (F1 - 1));
            int s = src[e], d = dst[e];
            float nrm = dinv[s] * dinv[d];
            atomicAdd(&x1[(long)d * F1 + f], nrm * W1[(long)s * F1 + f]);
        }
        for (long i = c3 + tid; i < c4; i += T) out4[i] = z4;
    }
    grid.sync();
    // ---- P5: layer1 + final out chunk
    {
        for (long i = tid; i < N; i += T) {
            float di = dinv[i], sw = di * di;
            float r[F1];
            #pragma unroll
            for (int f = 0; f < F1; ++f) {
                float v = x1[i * F1 + f] + sw * W1[i * F1 + f] + b1[f];
                r[f] = v > 0.f ? v : 0.f;
            }
            #pragma unroll
            for (int g = 0; g < F2; ++g) {
                float acc = 0.f;
                #pragma unroll
                for (int f = 0; f < F1; ++f) acc += r[f] * W2[f * F2 + g];
                h2[i * F2 + g] = acc;
            }
        }
        for (long i = c4 + tid; i < Z4; i += T) out4[i] = z4;
    }
    grid.sync();
    // ---- P6: conv2 edge atomics + scatter ones (out fully zeroed by now)
    {
        long W = (long)E * F2;
        for (long id = tid; id < W; id += T) {
            long e = id >> 3;
            int g = (int)(id & (F2 - 1));
            int s = src[e], d = dst[e];
            float nrm = dinv[s] * dinv[d];
            atomicAdd(&x2[(long)d * F2 + g], nrm * h2[(long)s * F2 + g]);
        }
        for (long e = tid; e < E; e += T)
            out[(long)src[e] * N + dst[e]] = 1.0f;
    }
    grid.sync();
    // ---- P7: orient (conv2 self term + bias + relu inline)
    {
        for (long k = tid; k < U; k += T) {
            int2 eu = ue[k];
            int u = eu.x, v = eu.y;
            float swu = dinv[u] * dinv[u], swv = dinv[v] * dinv[v];
            float s = bfc[0];
            #pragma unroll
            for (int g = 0; g < F2; ++g) {
                float xu = x2[u * F2 + g] + swu * h2[u * F2 + g] + b2[g];
                float xv = x2[v * F2 + g] + swv * h2[v * F2 + g] + b2[g];
                xu = xu > 0.f ? xu : 0.f;
                xv = xv > 0.f ? xv : 0.f;
                s += xu * Wfc[g] + xv * Wfc[F2 + g];
            }
            float orient = 1.f / (1.f + expf(-s));
            out[(long)u * N + v] = orient;
            out[(long)v * N + u] = 1.f - orient;
        }
    }
}

extern "C" void kernel_launch(void* const* d_in, const int* in_sizes, int n_in,
                              void* d_out, int out_size, void* d_ws, size_t ws_size,
                              hipStream_t stream) {
    const float* W1  = (const float*)d_in[1];
    const float* b1  = (const float*)d_in[2];
    const float* W2  = (const float*)d_in[3];
    const float* b2  = (const float*)d_in[4];
    const float* Wfc = (const float*)d_in[5];
    const float* bfc = (const float*)d_in[6];
    const int* edge_index = (const int*)d_in[7];
    const int2* und       = (const int2*)d_in[8];

    int N = in_sizes[1] / F1;      // 8192
    int E = in_sizes[7] / 2;
    int U = in_sizes[8] / 2;
    const int* src = edge_index;
    const int* dst = edge_index + E;

    float* out = (float*)d_out;
    float* ws  = (float*)d_ws;

    void* args[] = {
        (void*)&W1, (void*)&b1, (void*)&W2, (void*)&b2,
        (void*)&Wfc, (void*)&bfc, (void*)&src, (void*)&dst,
        (void*)&und, (void*)&out, (void*)&ws,
        (void*)&N, (void*)&E, (void*)&U
    };

    // 1024 blocks x 256 threads; __launch_bounds__(256,4) guarantees
    // 4 blocks/CU residency -> 1024 co-resident on 256 CUs.
    hipLaunchCooperativeKernel((void*)k_fused, dim3(1024), dim3(256),
                               args, 0, stream);
}

// Round 5
// 449.021 us; speedup vs baseline: 2.6663x; 2.6663x over previous
//
#include <hip/hip_runtime.h>
#include <math.h>

#define F1 16
#define F2 8

// Fused: scatter 1.0 at every directed edge position of out AND count in-degree.
__global__ void k_edges0(const int* __restrict__ src, const int* __restrict__ dst,
                         float* __restrict__ out, float* __restrict__ deg,
                         int E, int N) {
    int e = blockIdx.x * blockDim.x + threadIdx.x;
    if (e < E) {
        int s = src[e], d = dst[e];
        out[(long)s * N + d] = 1.0f;
        atomicAdd(&deg[d], 1.0f);
    }
}

// conv1 aggregation: x1[dst] += norm * W1[src]; norm computed inline from deg.
// (x1 pre-zeroed by memset; deg holds in-degree counts, +1 for self-loop)
__global__ void k_conv1_edges(const int* __restrict__ src, const int* __restrict__ dst,
                              const float* __restrict__ deg, const float* __restrict__ W1,
                              float* __restrict__ x1, int E) {
    int id = blockIdx.x * blockDim.x + threadIdx.x;
    int e = id >> 4;
    int f = id & (F1 - 1);
    if (e < E) {
        int s = src[e], d = dst[e];
        float nrm = rsqrtf((deg[s] + 1.0f) * (deg[d] + 1.0f));
        atomicAdd(&x1[(long)d * F1 + f], nrm * W1[(long)s * F1 + f]);
    }
}

// Per (node, out-feature): r = relu(x1 + W1/(deg+1) + b1); h2[i,g] = sum_f r[f]*W2[f,g]
__global__ void k_layer1(const float* __restrict__ deg, const float* __restrict__ b1,
                         const float* __restrict__ W1, const float* __restrict__ W2,
                         const float* __restrict__ x1, float* __restrict__ h2, int N) {
    int id = blockIdx.x * blockDim.x + threadIdx.x;
    if (id < N * F2) {
        int i = id >> 3;        // node
        int g = id & (F2 - 1);  // out feature
        float sw = 1.0f / (deg[i] + 1.0f);
        float acc = 0.0f;
        #pragma unroll
        for (int f = 0; f < F1; ++f) {
            float v = x1[(long)i * F1 + f] + sw * W1[(long)i * F1 + f] + b1[f];
            v = v > 0.0f ? v : 0.0f;
            acc += v * W2[f * F2 + g];
        }
        h2[(long)i * F2 + g] = acc;
    }
}

// conv2 aggregation: x2[dst] += norm * h2[src]; norm inline from deg.
__global__ void k_conv2_edges(const int* __restrict__ src, const int* __restrict__ dst,
                              const float* __restrict__ deg, const float* __restrict__ h2,
                              float* __restrict__ x2, int E) {
    int id = blockIdx.x * blockDim.x + threadIdx.x;
    int e = id >> 3;
    int g = id & (F2 - 1);
    if (e < E) {
        int s = src[e], d = dst[e];
        float nrm = rsqrtf((deg[s] + 1.0f) * (deg[d] + 1.0f));
        atomicAdd(&x2[(long)d * F2 + g], nrm * h2[(long)s * F2 + g]);
    }
}

// Per undirected edge: finish conv2 (self term + bias + relu) inline, score, scatter.
__global__ void k_orient(const int2* __restrict__ ue, const float* __restrict__ x2,
                         const float* __restrict__ h2, const float* __restrict__ deg,
                         const float* __restrict__ b2, const float* __restrict__ Wfc,
                         const float* __restrict__ bfc, float* __restrict__ out,
                         int U, int N) {
    int k = blockIdx.x * blockDim.x + threadIdx.x;
    if (k < U) {
        int2 e = ue[k];
        int u = e.x, v = e.y;
        float swu = 1.0f / (deg[u] + 1.0f);
        float swv = 1.0f / (deg[v] + 1.0f);
        float s = bfc[0];
        #pragma unroll
        for (int g = 0; g < F2; ++g) {
            float xu = x2[(long)u * F2 + g] + swu * h2[(long)u * F2 + g] + b2[g];
            float xv = x2[(long)v * F2 + g] + swv * h2[(long)v * F2 + g] + b2[g];
            xu = xu > 0.0f ? xu : 0.0f;
            xv = xv > 0.0f ? xv : 0.0f;
            s += xu * Wfc[g] + xv * Wfc[F2 + g];
        }
        float orient = 1.0f / (1.0f + expf(-s));
        out[(long)u * N + v] = orient;
        out[(long)v * N + u] = 1.0f - orient;
    }
}

extern "C" void kernel_launch(void* const* d_in, const int* in_sizes, int n_in,
                              void* d_out, int out_size, void* d_ws, size_t ws_size,
                              hipStream_t stream) {
    const float* W1  = (const float*)d_in[1];
    const float* b1  = (const float*)d_in[2];
    const float* W2  = (const float*)d_in[3];
    const float* b2  = (const float*)d_in[4];
    const float* Wfc = (const float*)d_in[5];
    const float* bfc = (const float*)d_in[6];
    const int* edge_index = (const int*)d_in[7];
    const int2* und       = (const int2*)d_in[8];

    int N = in_sizes[1] / F1;      // 8192
    int E = in_sizes[7] / 2;
    int U = in_sizes[8] / 2;
    const int* src = edge_index;
    const int* dst = edge_index + E;

    // ws layout: [deg(N) | x1(16N) | x2(8N)] (zeroed) | h2(8N) (written before read)
    float* ws  = (float*)d_ws;
    float* deg = ws;
    float* x1  = ws + N;
    float* x2  = x1 + (long)F1 * N;
    float* h2  = x2 + (long)F2 * N;

    const int B = 256;

    // Zero output (write-only; adjacency reconstructed exactly from edge_index
    // since A is 0/1 and edge_index = nonzero(A)).
    hipMemsetAsync(d_out, 0, (size_t)N * N * sizeof(float), stream);
    // Zero deg + x1 + x2 in one contiguous memset (800 KB).
    hipMemsetAsync(d_ws, 0, (size_t)(N + (long)F1 * N + (long)F2 * N) * sizeof(float), stream);

    // ones-scatter + degree count (fused)
    k_edges0<<<(E + B - 1) / B, B, 0, stream>>>(src, dst, (float*)d_out, deg, E, N);

    // conv1 aggregation (norm inline)
    {
        long work = (long)E * F1;
        k_conv1_edges<<<(int)((work + B - 1) / B), B, 0, stream>>>(src, dst, deg, W1, x1, E);
    }
    // layer1: relu + 16x8 matmul, (node, feature)-parallel
    k_layer1<<<(N * F2 + B - 1) / B, B, 0, stream>>>(deg, b1, W1, W2, x1, h2, N);

    // conv2 aggregation (norm inline)
    {
        long work = (long)E * F2;
        k_conv2_edges<<<(int)((work + B - 1) / B), B, 0, stream>>>(src, dst, deg, h2, x2, E);
    }

    // orient scoring + scatter (conv2 self term + bias + relu inline)
    k_orient<<<(U + B - 1) / B, B, 0, stream>>>(und, x2, h2, deg, b2, Wfc, bfc,
                                                (float*)d_out, U, N);
}